// Round 1
// baseline (417.168 us; speedup 1.0000x reference)
//
#include <hip/hip_runtime.h>
#include <math.h>

#define UNITS 1536
#define COLS  6144      // 4*UNITS
#define VOCAB 80
#define CHAR_LEN 256
#define NMIX 10
#define RCHUNK 32

__device__ __forceinline__ float sigmoidf_(float x) { return 1.0f / (1.0f + __expf(-x)); }

// Split-K GEMV partial: z = x@W + h@U over a row chunk, for 1024 cols per block-x tile.
// Virtual x vector for the W part: [inputs(3), wvec(80), hW(1536 if rowsW==1619)].
__global__ __launch_bounds__(256)
void gemv_partial(const float* __restrict__ W, const float* __restrict__ U,
                  const float* __restrict__ in3, const float* __restrict__ wv,
                  const float* __restrict__ hW, const float* __restrict__ hU,
                  int rowsW, int rowsTotal,
                  float* __restrict__ partials)
{
    const int col = (blockIdx.x * 256 + threadIdx.x) * 4;
    const int r0 = blockIdx.y * RCHUNK;
    int r1 = r0 + RCHUNK;
    if (r1 > rowsTotal) r1 = rowsTotal;

    float4 acc = make_float4(0.f, 0.f, 0.f, 0.f);
    for (int g = r0; g < r1; ++g) {
        float xv;
        const float* rp;
        if (g < rowsW) {
            xv = (g < 3) ? in3[g] : ((g < 83) ? wv[g - 3] : hW[g - 83]);
            rp = W + (size_t)g * COLS;
        } else {
            const int r = g - rowsW;
            xv = hU[r];
            rp = U + (size_t)r * COLS;
        }
        const float4 v = *reinterpret_cast<const float4*>(rp + col);
        acc.x = fmaf(xv, v.x, acc.x);
        acc.y = fmaf(xv, v.y, acc.y);
        acc.z = fmaf(xv, v.z, acc.z);
        acc.w = fmaf(xv, v.w, acc.w);
    }
    float* op = partials + (size_t)blockIdx.y * COLS + col;
    *reinterpret_cast<float4*>(op) = acc;
}

// Reduce partials over chunks, add bias, apply LSTM gates, write h_new.
// grid = 6 blocks x 1024 threads; block handles 256 h-outputs (all 4 gates).
__global__ __launch_bounds__(1024)
void gate_kernel(const float* __restrict__ partials, int nChunks,
                 const float* __restrict__ b, const float* __restrict__ c_in,
                 float* __restrict__ h_out)
{
    const int lane = threadIdx.x & 255;
    const int gate = threadIdx.x >> 8;     // 0=i 1=f 2=g 3=o
    const int j = blockIdx.x * 256 + lane; // 0..1535
    const int colIdx = gate * UNITS + j;

    float s = b[colIdx];
    for (int c = 0; c < nChunks; ++c)
        s += partials[(size_t)c * COLS + colIdx];

    __shared__ float zs[4][256];
    zs[gate][lane] = s;
    __syncthreads();
    if (gate == 0) {
        const float zi = zs[0][lane], zf = zs[1][lane], zg = zs[2][lane], zo = zs[3][lane];
        const float cn = sigmoidf_(zf) * c_in[j] + sigmoidf_(zi) * tanhf(zg);
        h_out[j] = sigmoidf_(zo) * tanhf(cn);
    }
}

// coef = h1n@Wd + bd ; attention window ; w = phi @ sentence. Single block of 256.
__global__ __launch_bounds__(256)
void window_kernel(const float* __restrict__ h1n, const float* __restrict__ Wd,
                   const float* __restrict__ bd, const float* __restrict__ kappa_prev,
                   const float* __restrict__ sentence, float* __restrict__ w_out)
{
    __shared__ float red[8][32];
    __shared__ float coef[32];
    __shared__ float al[NMIX], be[NMIX], ka[NMIX];
    __shared__ float phi[CHAR_LEN];

    const int t = threadIdx.x;
    const int j = t & 31;        // column 0..29 (30,31 idle)
    const int stripe = t >> 5;   // 0..7

    float acc = 0.f;
    if (j < 30) {
        for (int r = stripe; r < UNITS; r += 8)
            acc = fmaf(h1n[r], Wd[r * 30 + j], acc);
    }
    red[stripe][j] = acc;
    __syncthreads();

    if (t < 30) {
        float s = bd[t];
        #pragma unroll
        for (int k = 0; k < 8; ++k) s += red[k][t];
        coef[t] = s;
    }
    __syncthreads();

    if (t < NMIX) {
        al[t] = __expf(coef[t]);
        be[t] = __expf(coef[10 + t]);
        ka[t] = kappa_prev[t] + __expf(coef[20 + t]);
    }
    __syncthreads();

    {   // phi[u], u = t+1
        const float u = (float)(t + 1);
        float p = 0.f;
        #pragma unroll
        for (int k = 0; k < NMIX; ++k) {
            const float d = ka[k] - u;
            p += al[k] * __expf(-be[k] * d * d);
        }
        phi[t] = p;
    }
    __syncthreads();

    if (t < VOCAB) {
        float s = 0.f;
        for (int u = 0; u < CHAR_LEN; ++u)
            s = fmaf(phi[u], sentence[u * VOCAB + t], s);
        w_out[t] = s;
    }
}

extern "C" void kernel_launch(void* const* d_in, const int* in_sizes, int n_in,
                              void* d_out, int out_size, void* d_ws, size_t ws_size,
                              hipStream_t stream) {
    (void)in_sizes; (void)n_in; (void)out_size; (void)ws_size;

    const float* inputs     = (const float*)d_in[0];
    const float* h1         = (const float*)d_in[1];
    const float* c1         = (const float*)d_in[2];
    const float* h2         = (const float*)d_in[3];
    const float* c2         = (const float*)d_in[4];
    const float* h3         = (const float*)d_in[5];
    const float* c3         = (const float*)d_in[6];
    const float* w_prev     = (const float*)d_in[7];
    const float* kappa_prev = (const float*)d_in[8];
    const float* sentence   = (const float*)d_in[9];
    const float* W1 = (const float*)d_in[10];
    const float* U1 = (const float*)d_in[11];
    const float* b1 = (const float*)d_in[12];
    const float* Wd = (const float*)d_in[13];
    const float* bd = (const float*)d_in[14];
    const float* W2 = (const float*)d_in[15];
    const float* U2 = (const float*)d_in[16];
    const float* b2 = (const float*)d_in[17];
    const float* W3 = (const float*)d_in[18];
    const float* U3 = (const float*)d_in[19];
    const float* b3 = (const float*)d_in[20];

    float* out = (float*)d_out;         // [h1n | h2n | h3n]
    float* ws  = (float*)d_ws;
    float* w_vec    = ws;               // 80 floats (padded to 128)
    float* partials = ws + 128;         // up to 99 * 6144 floats (~2.4 MB)

    const int rows1  = 83 + UNITS;            // 1619
    const int rows23 = 83 + UNITS + UNITS;    // 3155
    const int ch1  = (rows1  + RCHUNK - 1) / RCHUNK;  // 51
    const int ch23 = (rows23 + RCHUNK - 1) / RCHUNK;  // 99

    const dim3 blk(256);

    // Phase 1: z1 = [inputs,w_prev]@W1 + h1@U1 -> h1n
    gemv_partial<<<dim3(6, ch1), blk, 0, stream>>>(W1, U1, inputs, w_prev, nullptr, h1,
                                                   83, rows1, partials);
    gate_kernel<<<6, 1024, 0, stream>>>(partials, ch1, b1, c1, out);

    // Attention window -> w_vec
    window_kernel<<<1, 256, 0, stream>>>(out, Wd, bd, kappa_prev, sentence, w_vec);

    // Phase 2: z2 = [inputs,w,h1n]@W2 + h2@U2 -> h2n
    gemv_partial<<<dim3(6, ch23), blk, 0, stream>>>(W2, U2, inputs, w_vec, out, h2,
                                                    1619, rows23, partials);
    gate_kernel<<<6, 1024, 0, stream>>>(partials, ch23, b2, c2, out + UNITS);

    // Phase 3: z3 = [inputs,w,h2n]@W3 + h3@U3 -> h3n
    gemv_partial<<<dim3(6, ch23), blk, 0, stream>>>(W3, U3, inputs, w_vec, out + UNITS, h3,
                                                    1619, rows23, partials);
    gate_kernel<<<6, 1024, 0, stream>>>(partials, ch23, b3, c3, out + 2 * UNITS);
}

// Round 3
// 276.034 us; speedup vs baseline: 1.5113x; 1.5113x over previous
//
#include <hip/hip_runtime.h>
#include <math.h>

#define UNITS 1536
#define COLS  6144      // 4*UNITS
#define VOCAB 80
#define CHAR_LEN 256
#define NMIX 10
#define RCHUNK 32

__device__ __forceinline__ float sigmoidf_(float x) { return 1.0f / (1.0f + __expf(-x)); }

// Split-K GEMV partial: z = x@W + h@U over a 32-row chunk, 1024 cols per x-block.
// Virtual x for W part: [inputs(3), wvec(80), hW(rest)]; U part multiplies hU.
__global__ __launch_bounds__(256)
void gemv_partial(const float* __restrict__ W, const float* __restrict__ U,
                  const float* __restrict__ in3, const float* __restrict__ wv,
                  const float* __restrict__ hW, const float* __restrict__ hU,
                  int rowsW, int rowsTotal,
                  float* __restrict__ partials)
{
    __shared__ float xs[RCHUNK];
    const int t = threadIdx.x;
    const int col = (blockIdx.x * 256 + t) * 4;
    const int r0 = blockIdx.y * RCHUNK;
    const int r1 = min(r0 + RCHUNK, rowsTotal);

    if (t < RCHUNK) {
        const int g = r0 + t;
        float xv = 0.f;
        if (g < rowsTotal) {
            if (g < rowsW) xv = (g < 3) ? in3[g] : ((g < 83) ? wv[g - 3] : hW[g - 83]);
            else           xv = hU[g - rowsW];
        }
        xs[t] = xv;
    }
    __syncthreads();

    float4 acc = make_float4(0.f, 0.f, 0.f, 0.f);
    const int endW = min(r1, rowsW);
    #pragma unroll 4
    for (int g = r0; g < endW; ++g) {
        const float4 v = *reinterpret_cast<const float4*>(W + (size_t)g * COLS + col);
        const float x = xs[g - r0];
        acc.x = fmaf(x, v.x, acc.x); acc.y = fmaf(x, v.y, acc.y);
        acc.z = fmaf(x, v.z, acc.z); acc.w = fmaf(x, v.w, acc.w);
    }
    const int startU = max(r0, rowsW);
    #pragma unroll 4
    for (int g = startU; g < r1; ++g) {
        const float4 v = *reinterpret_cast<const float4*>(U + (size_t)(g - rowsW) * COLS + col);
        const float x = xs[g - r0];
        acc.x = fmaf(x, v.x, acc.x); acc.y = fmaf(x, v.y, acc.y);
        acc.z = fmaf(x, v.z, acc.z); acc.w = fmaf(x, v.w, acc.w);
    }
    *reinterpret_cast<float4*>(partials + (size_t)blockIdx.y * COLS + col) = acc;
}

// Fused reduce + LSTM gate. grid = 24 blocks x 1024 threads.
// Block b owns h-columns j0 = b*64 .. +64 (all 4 gates, 4 chunk-stripes).
// If Wd != nullptr, also emits this block's 30-wide partial of h_new @ Wd.
__global__ __launch_bounds__(1024)
void gate_fused(const float* __restrict__ partials, int nChunks,
                const float* __restrict__ b, const float* __restrict__ c_in,
                float* __restrict__ h_out,
                const float* __restrict__ Wd, float* __restrict__ coefpart)
{
    __shared__ float red[4][4][64];
    __shared__ float zs[4][64];
    __shared__ float hs[64];
    __shared__ float red2[8][30];

    const int t = threadIdx.x;
    const int jj = t & 63;
    const int gate = (t >> 6) & 3;
    const int stripe = t >> 8;              // 0..3
    const int j0 = blockIdx.x * 64;
    const int col = gate * UNITS + j0 + jj;

    float s = 0.f;
    for (int c = stripe; c < nChunks; c += 4)
        s += partials[(size_t)c * COLS + col];
    red[stripe][gate][jj] = s;
    __syncthreads();

    if (t < 256) {  // stripe==0 threads
        const float z = b[col] + red[0][gate][jj] + red[1][gate][jj]
                               + red[2][gate][jj] + red[3][gate][jj];
        zs[gate][jj] = z;
    }
    __syncthreads();

    if (t < 64) {
        const float zi = zs[0][t], zf = zs[1][t], zg = zs[2][t], zo = zs[3][t];
        const float cn = sigmoidf_(zf) * c_in[j0 + t] + sigmoidf_(zi) * tanhf(zg);
        const float h = sigmoidf_(zo) * tanhf(cn);
        h_out[j0 + t] = h;
        hs[t] = h;
    }
    __syncthreads();

    if (Wd != nullptr) {
        if (t < 240) {                       // 8 stripes x 30 cols
            const int c30 = t % 30;
            const int rbase = (t / 30) * 8;
            float s2 = 0.f;
            #pragma unroll
            for (int k = 0; k < 8; ++k) {
                const int r = rbase + k;
                s2 = fmaf(hs[r], Wd[(size_t)(j0 + r) * 30 + c30], s2);
            }
            red2[t / 30][c30] = s2;
        }
        __syncthreads();
        if (t < 30) {
            float a = 0.f;
            #pragma unroll
            for (int k = 0; k < 8; ++k) a += red2[k][t];
            coefpart[blockIdx.x * 30 + t] = a;
        }
    }
}

// Reduce coef partials, compute attention window w = phi @ sentence.
// Single block of 1024 threads.
__global__ __launch_bounds__(1024)
void window_b(const float* __restrict__ coefpart, const float* __restrict__ bd,
              const float* __restrict__ kappa_prev, const float* __restrict__ sentence,
              float* __restrict__ w_out)
{
    __shared__ float coef[32];
    __shared__ float al[NMIX], be[NMIX], ka[NMIX];
    __shared__ float phi[CHAR_LEN];
    __shared__ float red[12][VOCAB];

    const int t = threadIdx.x;

    if (t < 30) {
        float s = bd[t];
        #pragma unroll
        for (int bb = 0; bb < 24; ++bb) s += coefpart[bb * 30 + t];
        coef[t] = s;
    }
    __syncthreads();

    if (t < NMIX) {
        al[t] = __expf(coef[t]);
        be[t] = __expf(coef[10 + t]);
        ka[t] = kappa_prev[t] + __expf(coef[20 + t]);
    }
    __syncthreads();

    if (t < CHAR_LEN) {
        const float u = (float)(t + 1);
        float p = 0.f;
        #pragma unroll
        for (int k = 0; k < NMIX; ++k) {
            const float d = ka[k] - u;
            p += al[k] * __expf(-be[k] * d * d);
        }
        phi[t] = p;
    }
    __syncthreads();

    if (t < 960) {                           // 12 stripes x 80 vocab cols
        const int v = t % 80;
        const int stripe = t / 80;
        float s = 0.f;
        for (int u = stripe; u < CHAR_LEN; u += 12)
            s = fmaf(phi[u], sentence[u * VOCAB + v], s);
        red[stripe][v] = s;
    }
    __syncthreads();

    if (t < VOCAB) {
        float s = 0.f;
        #pragma unroll
        for (int k = 0; k < 12; ++k) s += red[k][t];
        w_out[t] = s;
    }
}

extern "C" void kernel_launch(void* const* d_in, const int* in_sizes, int n_in,
                              void* d_out, int out_size, void* d_ws, size_t ws_size,
                              hipStream_t stream) {
    (void)in_sizes; (void)n_in; (void)out_size; (void)ws_size;

    const float* inputs     = (const float*)d_in[0];
    const float* h1         = (const float*)d_in[1];
    const float* c1         = (const float*)d_in[2];
    const float* h2         = (const float*)d_in[3];
    const float* c2         = (const float*)d_in[4];
    const float* h3         = (const float*)d_in[5];
    const float* c3         = (const float*)d_in[6];
    const float* w_prev     = (const float*)d_in[7];
    const float* kappa_prev = (const float*)d_in[8];
    const float* sentence   = (const float*)d_in[9];
    const float* W1 = (const float*)d_in[10];
    const float* U1 = (const float*)d_in[11];
    const float* b1 = (const float*)d_in[12];
    const float* Wd = (const float*)d_in[13];
    const float* bd = (const float*)d_in[14];
    const float* W2 = (const float*)d_in[15];
    const float* U2 = (const float*)d_in[16];
    const float* b2 = (const float*)d_in[17];
    const float* W3 = (const float*)d_in[18];
    const float* U3 = (const float*)d_in[19];
    const float* b3 = (const float*)d_in[20];

    float* out = (float*)d_out;          // [h1n | h2n | h3n]
    float* ws  = (float*)d_ws;
    float* w_vec    = ws;                // 80 floats (pad 128)
    float* coefpart = ws + 128;          // 24*30 floats (pad to 896)
    float* partials = ws + 1024;         // up to 99*6144 floats (~2.4 MB)

    const int rows1  = 83 + UNITS;             // 1619
    const int rows23 = 83 + UNITS + UNITS;     // 3155
    const int ch1  = (rows1  + RCHUNK - 1) / RCHUNK;   // 51
    const int ch23 = (rows23 + RCHUNK - 1) / RCHUNK;   // 99

    // Phase 1: z1 = [inputs,w_prev]@W1 + h1@U1 -> h1n (+ coef partials)
    gemv_partial<<<dim3(6, ch1), 256, 0, stream>>>(W1, U1, inputs, w_prev, nullptr, h1,
                                                   83, rows1, partials);
    gate_fused<<<24, 1024, 0, stream>>>(partials, ch1, b1, c1, out, Wd, coefpart);

    // Attention window -> w_vec
    window_b<<<1, 1024, 0, stream>>>(coefpart, bd, kappa_prev, sentence, w_vec);

    // Phase 2: z2 = [inputs,w,h1n]@W2 + h2@U2 -> h2n
    gemv_partial<<<dim3(6, ch23), 256, 0, stream>>>(W2, U2, inputs, w_vec, out, h2,
                                                    1619, rows23, partials);
    gate_fused<<<24, 1024, 0, stream>>>(partials, ch23, b2, c2, out + UNITS,
                                        nullptr, nullptr);

    // Phase 3: z3 = [inputs,w,h2n]@W3 + h3@U3 -> h3n
    gemv_partial<<<dim3(6, ch23), 256, 0, stream>>>(W3, U3, inputs, w_vec, out + UNITS, h3,
                                                    1619, rows23, partials);
    gate_fused<<<24, 1024, 0, stream>>>(partials, ch23, b3, c3, out + 2 * UNITS,
                                        nullptr, nullptr);
}

// Round 5
// 275.485 us; speedup vs baseline: 1.5143x; 1.0020x over previous
//
#include <hip/hip_runtime.h>
#include <math.h>

#define UNITS 1536
#define COLS  6144      // 4*UNITS
#define VOCAB 80
#define CHAR_LEN 256
#define NMIX 10

__device__ __forceinline__ float sigmoidf_(float x) { return 1.0f / (1.0f + __expf(-x)); }

// ---------------------------------------------------------------------------
// Mega-GEMV over all chain-independent rows, split-K into 32-row chunks.
// Virtual row space (padded to 32-row boundaries; pad rows: x=0, dummy ptr):
//   [0,83)      W1 rows, x=[inputs(3), w_prev(80)]
//   [83,1619)   U1 rows, x=h1
//   [1619,1632) pad
//   [1632,3168) U2 rows, x=h2
//   [3168,3171) W2 rows 0..2, x=inputs
//   [3171,3200) pad
//   [3200,4736) U3 rows, x=h3
//   [4736,4739) W3 rows 0..2, x=inputs
//   [4739,4768) pad                          -> 149 chunks total
// chunk -> partial slot: 0..50 -> p1[0..50]; 51..98 -> p2[0..47]; 99 -> p2[48];
//                        100..147 -> p3[0..47]; 148 -> p3[48]
// ---------------------------------------------------------------------------
__global__ __launch_bounds__(256)
void gemv_indep(const float* __restrict__ W1, const float* __restrict__ U1,
                const float* __restrict__ U2, const float* __restrict__ U3,
                const float* __restrict__ W2, const float* __restrict__ W3,
                const float* __restrict__ in3, const float* __restrict__ wp,
                const float* __restrict__ h1, const float* __restrict__ h2,
                const float* __restrict__ h3,
                float* __restrict__ p1, float* __restrict__ p2, float* __restrict__ p3)
{
    __shared__ const float* rps[32];
    __shared__ float xsh[32];
    const int t = threadIdx.x;
    const int cy = blockIdx.y;

    if (t < 32) {
        const int g = cy * 32 + t;
        const float* rp = W1;          // dummy valid row for pads
        float xv = 0.f;
        if (g < 83)        { rp = W1 + (size_t)g * COLS;          xv = (g < 3) ? in3[g] : wp[g - 3]; }
        else if (g < 1619) { rp = U1 + (size_t)(g - 83) * COLS;   xv = h1[g - 83]; }
        else if (g < 1632) { /* pad */ }
        else if (g < 3168) { rp = U2 + (size_t)(g - 1632) * COLS; xv = h2[g - 1632]; }
        else if (g < 3171) { rp = W2 + (size_t)(g - 3168) * COLS; xv = in3[g - 3168]; }
        else if (g < 3200) { /* pad */ }
        else if (g < 4736) { rp = U3 + (size_t)(g - 3200) * COLS; xv = h3[g - 3200]; }
        else if (g < 4739) { rp = W3 + (size_t)(g - 4736) * COLS; xv = in3[g - 4736]; }
        rps[t] = rp; xsh[t] = xv;
    }
    __syncthreads();

    const int col = (blockIdx.x * 256 + t) * 4;
    float4 acc = make_float4(0.f, 0.f, 0.f, 0.f);
    #pragma unroll 8
    for (int i = 0; i < 32; ++i) {
        const float4 v = *reinterpret_cast<const float4*>(rps[i] + col);
        const float x = xsh[i];
        acc.x = fmaf(x, v.x, acc.x); acc.y = fmaf(x, v.y, acc.y);
        acc.z = fmaf(x, v.z, acc.z); acc.w = fmaf(x, v.w, acc.w);
    }

    float* zone; int slot;
    if (cy < 51)       { zone = p1; slot = cy; }
    else if (cy < 99)  { zone = p2; slot = cy - 51; }
    else if (cy == 99) { zone = p2; slot = 48; }
    else if (cy < 148) { zone = p3; slot = cy - 100; }
    else               { zone = p3; slot = 48; }
    *reinterpret_cast<float4*>(zone + (size_t)slot * COLS + col) = acc;
}

// Dependent rows of layer L: [w(80), h_prev(1536)] @ W rows 3..1618 (1616 rows,
// 51 chunks, last half-padded). Writes zoneBase + cy*COLS (caller offsets slot 49).
__global__ __launch_bounds__(256)
void gemv_dep(const float* __restrict__ W, const float* __restrict__ wv,
              const float* __restrict__ hp, float* __restrict__ zoneBase)
{
    __shared__ const float* rps[32];
    __shared__ float xsh[32];
    const int t = threadIdx.x;
    const int cy = blockIdx.y;

    if (t < 32) {
        const int g2 = cy * 32 + t;
        const float* rp = W + 3 * COLS;
        float xv = 0.f;
        if (g2 < 80)        { rp = W + (size_t)(3 + g2) * COLS; xv = wv[g2]; }
        else if (g2 < 1616) { rp = W + (size_t)(3 + g2) * COLS; xv = hp[g2 - 80]; }
        rps[t] = rp; xsh[t] = xv;
    }
    __syncthreads();

    const int col = (blockIdx.x * 256 + t) * 4;
    float4 acc = make_float4(0.f, 0.f, 0.f, 0.f);
    #pragma unroll 8
    for (int i = 0; i < 32; ++i) {
        const float4 v = *reinterpret_cast<const float4*>(rps[i] + col);
        const float x = xsh[i];
        acc.x = fmaf(x, v.x, acc.x); acc.y = fmaf(x, v.y, acc.y);
        acc.z = fmaf(x, v.z, acc.z); acc.w = fmaf(x, v.w, acc.w);
    }
    *reinterpret_cast<float4*>(zoneBase + (size_t)cy * COLS + col) = acc;
}

// Fused reduce + LSTM gate. grid = 24 blocks x 1024 threads.
// Block b owns h-columns j0 = b*64 .. +64 (4 gates x 4 chunk-stripes).
// If Wd != nullptr, also emits this block's 30-wide partial of h_new @ Wd.
__global__ __launch_bounds__(1024)
void gate_fused(const float* __restrict__ partials, int nChunks,
                const float* __restrict__ b, const float* __restrict__ c_in,
                float* __restrict__ h_out,
                const float* __restrict__ Wd, float* __restrict__ coefpart)
{
    __shared__ float red[4][4][64];
    __shared__ float zs[4][64];
    __shared__ float hs[64];
    __shared__ float red2[8][30];

    const int t = threadIdx.x;
    const int jj = t & 63;
    const int gate = (t >> 6) & 3;
    const int stripe = t >> 8;              // 0..3
    const int j0 = blockIdx.x * 64;
    const int col = gate * UNITS + j0 + jj;

    float s = 0.f;
    for (int c = stripe; c < nChunks; c += 4)
        s += partials[(size_t)c * COLS + col];
    red[stripe][gate][jj] = s;
    __syncthreads();

    if (t < 256) {
        const float z = b[col] + red[0][gate][jj] + red[1][gate][jj]
                               + red[2][gate][jj] + red[3][gate][jj];
        zs[gate][jj] = z;
    }
    __syncthreads();

    if (t < 64) {
        const float zi = zs[0][t], zf = zs[1][t], zg = zs[2][t], zo = zs[3][t];
        const float cn = sigmoidf_(zf) * c_in[j0 + t] + sigmoidf_(zi) * tanhf(zg);
        const float h = sigmoidf_(zo) * tanhf(cn);
        h_out[j0 + t] = h;
        hs[t] = h;
    }
    __syncthreads();

    if (Wd != nullptr) {
        if (t < 240) {                       // 8 stripes x 30 cols
            const int c30 = t % 30;
            const int rbase = (t / 30) * 8;
            float s2 = 0.f;
            #pragma unroll
            for (int k = 0; k < 8; ++k) {
                const int r = rbase + k;
                s2 = fmaf(hs[r], Wd[(size_t)(j0 + r) * 30 + c30], s2);
            }
            red2[t / 30][c30] = s2;
        }
        __syncthreads();
        if (t < 30) {
            float a = 0.f;
            #pragma unroll
            for (int k = 0; k < 8; ++k) a += red2[k][t];
            coefpart[blockIdx.x * 30 + t] = a;
        }
    }
}

// Reduce coef partials, attention window, w = phi @ sentence. 1 block x 1024.
__global__ __launch_bounds__(1024)
void window_b(const float* __restrict__ coefpart, const float* __restrict__ bd,
              const float* __restrict__ kappa_prev, const float* __restrict__ sentence,
              float* __restrict__ w_out)
{
    __shared__ float coef[32];
    __shared__ float al[NMIX], be[NMIX], ka[NMIX];
    __shared__ float phi[CHAR_LEN];
    __shared__ float red[12][VOCAB];

    const int t = threadIdx.x;

    if (t < 30) {
        float s = bd[t];
        #pragma unroll
        for (int bb = 0; bb < 24; ++bb) s += coefpart[bb * 30 + t];
        coef[t] = s;
    }
    __syncthreads();

    if (t < NMIX) {
        al[t] = __expf(coef[t]);
        be[t] = __expf(coef[10 + t]);
        ka[t] = kappa_prev[t] + __expf(coef[20 + t]);
    }
    __syncthreads();

    if (t < CHAR_LEN) {
        const float u = (float)(t + 1);
        float p = 0.f;
        #pragma unroll
        for (int k = 0; k < NMIX; ++k) {
            const float d = ka[k] - u;
            p += al[k] * __expf(-be[k] * d * d);
        }
        phi[t] = p;
    }
    __syncthreads();

    if (t < 960) {                           // 12 stripes x 80 vocab cols
        const int v = t % 80;
        const int stripe = t / 80;
        float s = 0.f;
        for (int u = stripe; u < CHAR_LEN; u += 12)
            s = fmaf(phi[u], sentence[u * VOCAB + v], s);
        red[stripe][v] = s;
    }
    __syncthreads();

    if (t < VOCAB) {
        float s = 0.f;
        #pragma unroll
        for (int k = 0; k < 12; ++k) s += red[k][t];
        w_out[t] = s;
    }
}

extern "C" void kernel_launch(void* const* d_in, const int* in_sizes, int n_in,
                              void* d_out, int out_size, void* d_ws, size_t ws_size,
                              hipStream_t stream) {
    (void)in_sizes; (void)n_in; (void)out_size; (void)ws_size;

    const float* inputs     = (const float*)d_in[0];
    const float* h1         = (const float*)d_in[1];
    const float* c1         = (const float*)d_in[2];
    const float* h2         = (const float*)d_in[3];
    const float* c2         = (const float*)d_in[4];
    const float* h3         = (const float*)d_in[5];
    const float* c3         = (const float*)d_in[6];
    const float* w_prev     = (const float*)d_in[7];
    const float* kappa_prev = (const float*)d_in[8];
    const float* sentence   = (const float*)d_in[9];
    const float* W1 = (const float*)d_in[10];
    const float* U1 = (const float*)d_in[11];
    const float* b1 = (const float*)d_in[12];
    const float* Wd = (const float*)d_in[13];
    const float* bd = (const float*)d_in[14];
    const float* W2 = (const float*)d_in[15];
    const float* U2 = (const float*)d_in[16];
    const float* b2 = (const float*)d_in[17];
    const float* W3 = (const float*)d_in[18];
    const float* U3 = (const float*)d_in[19];
    const float* b3 = (const float*)d_in[20];

    float* out = (float*)d_out;          // [h1n | h2n | h3n]
    float* ws  = (float*)d_ws;
    float* w_vec    = ws;                // 80 floats (pad 128)
    float* coefpart = ws + 128;          // 24*30 floats (pad to 896)
    float* pbase    = ws + 1024;
    float* p1 = pbase;                   // 51 slots  x 6144
    float* p2 = pbase + (size_t)51  * COLS;  // 100 slots x 6144
    float* p3 = pbase + (size_t)151 * COLS;  // 100 slots x 6144

    // A: all chain-independent GEMV rows (z1 full + h2@U2 + h3@U3 + inputs@W2/W3)
    gemv_indep<<<dim3(6, 149), 256, 0, stream>>>(W1, U1, U2, U3, W2, W3,
                                                 inputs, w_prev, h1, h2, h3,
                                                 p1, p2, p3);
    // gate1 -> h1n (+ coef partials)
    gate_fused<<<24, 1024, 0, stream>>>(p1, 51, b1, c1, out, Wd, coefpart);
    // window -> w_vec
    window_b<<<1, 1024, 0, stream>>>(coefpart, bd, kappa_prev, sentence, w_vec);
    // dependent z2 rows: [w, h1n] @ W2 rows 3..1618 -> p2 slots 49..99
    gemv_dep<<<dim3(6, 51), 256, 0, stream>>>(W2, w_vec, out, p2 + (size_t)49 * COLS);
    gate_fused<<<24, 1024, 0, stream>>>(p2, 100, b2, c2, out + UNITS, nullptr, nullptr);
    // dependent z3 rows: [w, h2n] @ W3 rows 3..1618 -> p3 slots 49..99
    gemv_dep<<<dim3(6, 51), 256, 0, stream>>>(W3, w_vec, out + UNITS, p3 + (size_t)49 * COLS);
    gate_fused<<<24, 1024, 0, stream>>>(p3, 100, b3, c3, out + 2 * UNITS, nullptr, nullptr);
}

// Round 6
// 268.901 us; speedup vs baseline: 1.5514x; 1.0245x over previous
//
#include <hip/hip_runtime.h>
#include <math.h>

#define UNITS 1536
#define COLS  6144      // 4*UNITS
#define VOCAB 80
#define CHAR_LEN 256
#define NMIX 10

__device__ __forceinline__ float sigmoidf_(float x) { return 1.0f / (1.0f + __expf(-x)); }

// Hoist a block-uniform pointer (read from LDS) into SGPRs so global loads use
// scalar base + shared voffset instead of per-lane 64-bit addresses.
__device__ __forceinline__ const float* rfl_ptr(const float* p) {
    unsigned long long u = (unsigned long long)p;
    unsigned lo = __builtin_amdgcn_readfirstlane((unsigned)u);
    unsigned hi = __builtin_amdgcn_readfirstlane((unsigned)(u >> 32));
    return (const float*)(((unsigned long long)hi << 32) | lo);
}

// 8-wide load batch then FMA, explicit MLP.
#define GEMV_BATCH(BASE)                                                     \
    {                                                                        \
        float4 v[8];                                                         \
        _Pragma("unroll")                                                    \
        for (int i = 0; i < 8; ++i)                                          \
            v[i] = *reinterpret_cast<const float4*>(rfl_ptr(rps[BASE + i]) + col); \
        _Pragma("unroll")                                                    \
        for (int i = 0; i < 8; ++i) {                                        \
            const float x = xsh[BASE + i];                                   \
            acc.x = fmaf(x, v[i].x, acc.x); acc.y = fmaf(x, v[i].y, acc.y);  \
            acc.z = fmaf(x, v[i].z, acc.z); acc.w = fmaf(x, v[i].w, acc.w);  \
        }                                                                    \
    }

// ---------------------------------------------------------------------------
// Mega-GEMV over all chain-independent rows, split-K into 16-row chunks.
// cy < 102 : p1 slot cy       rows g=cy*16+i: [0,83) W1 (x=[in3,w_prev]),
//                                             [83,1619) U1 (x=h1), pad to 1632
// cy < 199 : p2 slot cy-102   g=(cy-102)*16+i: [0,1536) U2 (x=h2),
//                                             [1536,1539) W2 rows 0..2 (x=in3), pad
// cy < 296 : p3 slot cy-199   same with U3/W3 (x=h3)
// ---------------------------------------------------------------------------
__global__ __launch_bounds__(256, 6)
void gemv_indep(const float* __restrict__ W1, const float* __restrict__ U1,
                const float* __restrict__ U2, const float* __restrict__ U3,
                const float* __restrict__ W2, const float* __restrict__ W3,
                const float* __restrict__ in3, const float* __restrict__ wp,
                const float* __restrict__ h1, const float* __restrict__ h2,
                const float* __restrict__ h3,
                float* __restrict__ p1, float* __restrict__ p2, float* __restrict__ p3)
{
    __shared__ const float* rps[16];
    __shared__ float xsh[16];
    const int t = threadIdx.x;
    const int cy = blockIdx.y;

    if (t < 16) {
        const float* rp = W1;              // dummy valid row for pads
        float xv = 0.f;
        if (cy < 102) {
            const int g = cy * 16 + t;
            if (g < 83)        { rp = W1 + (size_t)g * COLS;        xv = (g < 3) ? in3[g] : wp[g - 3]; }
            else if (g < 1619) { rp = U1 + (size_t)(g - 83) * COLS; xv = h1[g - 83]; }
        } else if (cy < 199) {
            const int g = (cy - 102) * 16 + t;
            if (g < 1536)      { rp = U2 + (size_t)g * COLS;          xv = h2[g]; }
            else if (g < 1539) { rp = W2 + (size_t)(g - 1536) * COLS; xv = in3[g - 1536]; }
        } else {
            const int g = (cy - 199) * 16 + t;
            if (g < 1536)      { rp = U3 + (size_t)g * COLS;          xv = h3[g]; }
            else if (g < 1539) { rp = W3 + (size_t)(g - 1536) * COLS; xv = in3[g - 1536]; }
        }
        rps[t] = rp; xsh[t] = xv;
    }
    __syncthreads();

    const int col = (blockIdx.x * 256 + t) * 4;
    float4 acc = make_float4(0.f, 0.f, 0.f, 0.f);
    GEMV_BATCH(0)
    GEMV_BATCH(8)

    float* zone; int slot;
    if (cy < 102)      { zone = p1; slot = cy; }
    else if (cy < 199) { zone = p2; slot = cy - 102; }
    else               { zone = p3; slot = cy - 199; }
    *reinterpret_cast<float4*>(zone + (size_t)slot * COLS + col) = acc;
}

// Dependent rows of a layer: [w(80), h_prev(1536)] @ W rows 3..1618.
// 1616 rows = 101 chunks of 16 exactly. Writes zoneBase + cy*COLS.
__global__ __launch_bounds__(256, 6)
void gemv_dep(const float* __restrict__ W, const float* __restrict__ wv,
              const float* __restrict__ hp, float* __restrict__ zoneBase)
{
    __shared__ const float* rps[16];
    __shared__ float xsh[16];
    const int t = threadIdx.x;
    const int cy = blockIdx.y;

    if (t < 16) {
        const int g2 = cy * 16 + t;        // 0..1615, always valid
        rps[t] = W + (size_t)(3 + g2) * COLS;
        xsh[t] = (g2 < 80) ? wv[g2] : hp[g2 - 80];
    }
    __syncthreads();

    const int col = (blockIdx.x * 256 + t) * 4;
    float4 acc = make_float4(0.f, 0.f, 0.f, 0.f);
    GEMV_BATCH(0)
    GEMV_BATCH(8)
    *reinterpret_cast<float4*>(zoneBase + (size_t)cy * COLS + col) = acc;
}

// Fused reduce + LSTM gate. grid = 96 blocks x 1024 threads.
// Block owns 16 h-columns j0=bx*16; threads = 16 jj x 4 gates x 16 stripes.
// If Wd != nullptr, also emits this block's 30-wide partial of h_new @ Wd.
__global__ __launch_bounds__(1024)
void gate_fused(const float* __restrict__ partials, int nChunks,
                const float* __restrict__ b, const float* __restrict__ c_in,
                float* __restrict__ h_out,
                const float* __restrict__ Wd, float* __restrict__ coefpart)
{
    __shared__ float red[16][4][16];
    __shared__ float zs[4][16];
    __shared__ float hs[16];
    __shared__ float red2[16][30];

    const int t = threadIdx.x;
    const int jj = t & 15;
    const int gate = (t >> 4) & 3;
    const int stripe = t >> 6;              // 0..15
    const int j0 = blockIdx.x * 16;
    const int col = gate * UNITS + j0 + jj;

    float s = 0.f;
    for (int c = stripe; c < nChunks; c += 16)
        s += partials[(size_t)c * COLS + col];
    red[stripe][gate][jj] = s;
    __syncthreads();

    if (t < 64) {
        const int g2 = t >> 4, j2 = t & 15;
        float z = b[g2 * UNITS + j0 + j2];
        #pragma unroll
        for (int k = 0; k < 16; ++k) z += red[k][g2][j2];
        zs[g2][j2] = z;
    }
    __syncthreads();

    if (t < 16) {
        const float zi = zs[0][t], zf = zs[1][t], zg = zs[2][t], zo = zs[3][t];
        const float cn = sigmoidf_(zf) * c_in[j0 + t] + sigmoidf_(zi) * tanhf(zg);
        const float h = sigmoidf_(zo) * tanhf(cn);
        h_out[j0 + t] = h;
        hs[t] = h;
    }
    __syncthreads();

    if (Wd != nullptr) {
        if (t < 480) {                       // 16 rows x 30 cols
            const int r = t / 30, c30 = t % 30;
            red2[r][c30] = hs[r] * Wd[(size_t)(j0 + r) * 30 + c30];
        }
        __syncthreads();
        if (t < 30) {
            float a = 0.f;
            #pragma unroll
            for (int k = 0; k < 16; ++k) a += red2[k][t];
            coefpart[blockIdx.x * 30 + t] = a;
        }
    }
}

// Reduce coef partials, attention window, w = phi @ sentence. 1 block x 1024.
__global__ __launch_bounds__(1024)
void window_b(const float* __restrict__ coefpart, const float* __restrict__ bd,
              const float* __restrict__ kappa_prev, const float* __restrict__ sentence,
              float* __restrict__ w_out)
{
    __shared__ float coef[32];
    __shared__ float al[NMIX], be[NMIX], ka[NMIX];
    __shared__ float phi[CHAR_LEN];
    __shared__ float red[12][VOCAB];

    const int t = threadIdx.x;

    if (t < 30) {
        float s = bd[t];
        for (int bb = 0; bb < 96; ++bb) s += coefpart[bb * 30 + t];
        coef[t] = s;
    }
    __syncthreads();

    if (t < NMIX) {
        al[t] = __expf(coef[t]);
        be[t] = __expf(coef[10 + t]);
        ka[t] = kappa_prev[t] + __expf(coef[20 + t]);
    }
    __syncthreads();

    if (t < CHAR_LEN) {
        const float u = (float)(t + 1);
        float p = 0.f;
        #pragma unroll
        for (int k = 0; k < NMIX; ++k) {
            const float d = ka[k] - u;
            p += al[k] * __expf(-be[k] * d * d);
        }
        phi[t] = p;
    }
    __syncthreads();

    if (t < 960) {                           // 12 stripes x 80 vocab cols
        const int v = t % 80;
        const int stripe = t / 80;
        float s = 0.f;
        for (int u = stripe; u < CHAR_LEN; u += 12)
            s = fmaf(phi[u], sentence[u * VOCAB + v], s);
        red[stripe][v] = s;
    }
    __syncthreads();

    if (t < VOCAB) {
        float s = 0.f;
        #pragma unroll
        for (int k = 0; k < 12; ++k) s += red[k][t];
        w_out[t] = s;
    }
}

extern "C" void kernel_launch(void* const* d_in, const int* in_sizes, int n_in,
                              void* d_out, int out_size, void* d_ws, size_t ws_size,
                              hipStream_t stream) {
    (void)in_sizes; (void)n_in; (void)out_size; (void)ws_size;

    const float* inputs     = (const float*)d_in[0];
    const float* h1         = (const float*)d_in[1];
    const float* c1         = (const float*)d_in[2];
    const float* h2         = (const float*)d_in[3];
    const float* c2         = (const float*)d_in[4];
    const float* h3         = (const float*)d_in[5];
    const float* c3         = (const float*)d_in[6];
    const float* w_prev     = (const float*)d_in[7];
    const float* kappa_prev = (const float*)d_in[8];
    const float* sentence   = (const float*)d_in[9];
    const float* W1 = (const float*)d_in[10];
    const float* U1 = (const float*)d_in[11];
    const float* b1 = (const float*)d_in[12];
    const float* Wd = (const float*)d_in[13];
    const float* bd = (const float*)d_in[14];
    const float* W2 = (const float*)d_in[15];
    const float* U2 = (const float*)d_in[16];
    const float* b2 = (const float*)d_in[17];
    const float* W3 = (const float*)d_in[18];
    const float* U3 = (const float*)d_in[19];
    const float* b3 = (const float*)d_in[20];

    float* out = (float*)d_out;          // [h1n | h2n | h3n]
    float* ws  = (float*)d_ws;
    float* w_vec    = ws;                // 80 floats (pad 128)
    float* coefpart = ws + 128;          // 96*30 floats
    float* pbase    = ws + 4096;
    float* p1 = pbase;                        // 102 slots x 6144
    float* p2 = pbase + (size_t)102 * COLS;   // 198 slots x 6144
    float* p3 = pbase + (size_t)300 * COLS;   // 198 slots x 6144

    // A: all chain-independent GEMV rows (z1 full + h2@U2 + h3@U3 + inputs@W2/W3)
    gemv_indep<<<dim3(6, 296), 256, 0, stream>>>(W1, U1, U2, U3, W2, W3,
                                                 inputs, w_prev, h1, h2, h3,
                                                 p1, p2, p3);
    // gate1 -> h1n (+ coef partials)
    gate_fused<<<96, 1024, 0, stream>>>(p1, 102, b1, c1, out, Wd, coefpart);
    // window -> w_vec
    window_b<<<1, 1024, 0, stream>>>(coefpart, bd, kappa_prev, sentence, w_vec);
    // dependent z2 rows: [w, h1n] @ W2 rows 3..1618 -> p2 slots 97..197
    gemv_dep<<<dim3(6, 101), 256, 0, stream>>>(W2, w_vec, out, p2 + (size_t)97 * COLS);
    gate_fused<<<96, 1024, 0, stream>>>(p2, 198, b2, c2, out + UNITS, nullptr, nullptr);
    // dependent z3 rows: [w, h2n] @ W3 rows 3..1618 -> p3 slots 97..197
    gemv_dep<<<dim3(6, 101), 256, 0, stream>>>(W3, w_vec, out + UNITS, p3 + (size_t)97 * COLS);
    gate_fused<<<96, 1024, 0, stream>>>(p3, 198, b3, c3, out + 2 * UNITS, nullptr, nullptr);
}